// Round 4
// baseline (349.985 us; speedup 1.0000x reference)
//
#include <hip/hip_runtime.h>
#include <stdint.h>

#define NHEAD 16
#define DKH 64
#define BBATCH 4
#define SEQ 2048
#define MROWS (BBATCH*SEQ)   // 8192
#define DMODEL 1024

typedef __attribute__((ext_vector_type(8))) __bf16 bf16x8;
typedef __attribute__((ext_vector_type(4))) float f32x4;

__device__ __forceinline__ unsigned short f2bf(float x) {
  unsigned int u = __float_as_uint(x);
  u += 0x7FFFu + ((u >> 16) & 1u);          // RN-even
  return (unsigned short)(u >> 16);
}
// pack bf16(a) | bf16(b)<<16, round-half-up: 2 adds + 1 v_perm
__device__ __forceinline__ unsigned int pkbf(float a, float b) {
  return __builtin_amdgcn_perm(__float_as_uint(b) + 0x8000u,
                               __float_as_uint(a) + 0x8000u, 0x07060302u);
}
// truncating pack (1 v_perm). Used only for P: downward bias cancels in
// softmax normalization because l (ones-MFMA) sums the same truncated values.
__device__ __forceinline__ unsigned int pkbf_t(float a, float b) {
  return __builtin_amdgcn_perm(__float_as_uint(b), __float_as_uint(a), 0x07060302u);
}
__device__ __forceinline__ void gl_lds16(const void* g, void* l) {
  __builtin_amdgcn_global_load_lds(
      (const __attribute__((address_space(1))) unsigned int*)g,
      (__attribute__((address_space(3))) unsigned int*)l, 16, 0, 0);
}
__device__ __forceinline__ f32x4 mfma16(bf16x8 a, bf16x8 b, f32x4 c) {
  return __builtin_amdgcn_mfma_f32_16x16x32_bf16(a, b, c, 0, 0, 0);
}

// ---------- fp32 -> bf16 convert for the 4 weight matrices only ----------
// q/k/v conversion is fused into proj_gemm's A-staging (R3): saves the
// 96MB fp32 read + 48MB bf16 write + a kernel launch of the old cvt_all.
__global__ __launch_bounds__(256) void cvt_w(
    const float* __restrict__ s3, const float* __restrict__ s4,
    const float* __restrict__ s5, const float* __restrict__ s6,
    unsigned short* __restrict__ d3, unsigned short* __restrict__ d4,
    unsigned short* __restrict__ d5, unsigned short* __restrict__ d6) {
  const int NW = 262144;    // float4 groups in each W
  int i = blockIdx.x * 256 + threadIdx.x;
  const float* src; unsigned short* dst; int off;
  if      (i < NW)     { src = s3; dst = d3; off = i; }
  else if (i < 2*NW)   { src = s4; dst = d4; off = i - NW; }
  else if (i < 3*NW)   { src = s5; dst = d5; off = i - 2*NW; }
  else                 { src = s6; dst = d6; off = i - 3*NW; }
  float4 x = ((const float4*)src)[off];
  uint2 o; o.x = pkbf(x.x, x.y); o.y = pkbf(x.z, x.w);
  ((uint2*)dst)[off] = o;
}

// ---------- fused cvt + Q/K/V projection GEMM: Y = to_bf16(X) @ W^T ----------
// A is the RAW fp32 input; staged via registers with fp32->bf16 convert
// (T14 split): issue A(kk+1) global loads early, convert+ds_write late,
// so HBM/L3 latency hides under compute(kk). B (bf16 W) stays on the
// global_load_lds path. Double-buffered, ONE barrier/iter.
// LDS layout identical to R2 (row r: 8 chunks of 8, chunk slot s holds
// source chunk s^(r&7)) -> fragment reads unchanged.
// A fp32 re-reads (x8 bn-blocks) are L3-resident (q,k,v = 96MB < 256MB L3).
// z=0: Q -> [B,H,S,64] scaled by 0.125*log2e; z=1: K; z=2: V^T [B,H,64,S].
__global__ __launch_bounds__(256, 2) void proj_gemm(
    const float* __restrict__ A0, const float* __restrict__ A1,
    const float* __restrict__ A2,
    const unsigned short* __restrict__ B0, const unsigned short* __restrict__ B1,
    const unsigned short* __restrict__ B2,
    unsigned short* __restrict__ O0, unsigned short* __restrict__ O1,
    unsigned short* __restrict__ O2) {
  // [buf][ A: 0..8191 | B: 8192..16383 ]; buf0 doubles as transpose scratch (z=2)
  __shared__ __align__(16) unsigned short smem[2][16384]; // 64KB
  const int z = blockIdx.z;
  const float* Ah = (z == 0) ? A0 : ((z == 1) ? A1 : A2);
  const unsigned short* Bh = (z == 0) ? B0 : ((z == 1) ? B1 : B2);
  unsigned short* outp = (z == 0) ? O0 : ((z == 1) ? O1 : O2);
  const int t = threadIdx.x;
  const int bm = blockIdx.x, bn = blockIdx.y;
  const int lane = t & 63, lm = lane & 15, quad = lane >> 4;
  const int w = t >> 6, wr = w >> 1, wc = w & 1;

  f32x4 acc[4][4];
#pragma unroll
  for (int i = 0; i < 4; ++i)
#pragma unroll
    for (int j = 0; j < 4; ++j) acc[i][j] = (f32x4){0.f, 0.f, 0.f, 0.f};

  // per-thread A/B addressing, kk-invariant parts hoisted
  float4 ar[8];                              // A(kk+1) in flight, fp32
  auto loadA = [&](int kk) {
#pragma unroll
    for (int jj = 0; jj < 4; ++jj) {
      int cid = jj * 256 + t;                // 0..1023
      int r = cid >> 3, c = cid & 7;
      int gcol = kk * 64 + ((c ^ (r & 7)) * 8);
      const float4* src = (const float4*)(Ah + (bm * 128 + r) * 1024 + gcol);
      ar[2 * jj]     = src[0];
      ar[2 * jj + 1] = src[1];
    }
  };
  auto writeA = [&](int b) {
#pragma unroll
    for (int jj = 0; jj < 4; ++jj) {
      int cid = jj * 256 + t;
      uint4 wv;
      wv.x = pkbf(ar[2 * jj].x,     ar[2 * jj].y);
      wv.y = pkbf(ar[2 * jj].z,     ar[2 * jj].w);
      wv.z = pkbf(ar[2 * jj + 1].x, ar[2 * jj + 1].y);
      wv.w = pkbf(ar[2 * jj + 1].z, ar[2 * jj + 1].w);
      *(uint4*)(&smem[b][cid * 8]) = wv;     // same dest layout as gl_lds path
    }
  };
  auto stageB = [&](int kk, int b) {
#pragma unroll
    for (int jj = 0; jj < 4; ++jj) {
      int cid = jj * 256 + t;
      int r = cid >> 3, c = cid & 7;
      int gcol = kk * 64 + ((c ^ (r & 7)) * 8);
      gl_lds16(Bh + (bn * 128 + r) * 1024 + gcol, &smem[b][8192 + cid * 8]);
    }
  };

  // prologue: tile 0 into buf 0
  loadA(0);
  stageB(0, 0);
  writeA(0);
  __syncthreads();

  for (int kk = 0; kk < 16; ++kk) {
    const int cur = kk & 1;
    if (kk < 15) {
      loadA(kk + 1);              // fp32 A -> regs, latency hidden by compute
      stageB(kk + 1, cur ^ 1);    // bf16 W -> LDS, async
    }
    const unsigned short* sA = &smem[cur][0];
    const unsigned short* sB = &smem[cur][8192];
#pragma unroll
    for (int kc = 0; kc < 2; ++kc) {
      bf16x8 af[4], bf[4];
#pragma unroll
      for (int i = 0; i < 4; ++i) {
        int m = wr * 64 + i * 16 + lm;
        int nn = wc * 64 + i * 16 + lm;
        int slot = ((kc * 4 + quad) ^ (lm & 7)) * 8;
        af[i] = *(const bf16x8*)(sA + m * 64 + slot);
        bf[i] = *(const bf16x8*)(sB + nn * 64 + slot);
      }
#pragma unroll
      for (int i = 0; i < 4; ++i)
#pragma unroll
        for (int j = 0; j < 4; ++j) acc[i][j] = mfma16(af[i], bf[j], acc[i][j]);
    }
    if (kk < 15) writeA(cur ^ 1); // convert + ds_write into next buffer
    __syncthreads();              // drains vmcnt (B) + lgkm (A writes) + reads
  }

  if (z < 2) {
    float scale = (z == 0) ? 0.125f * 1.44269504f : 1.0f;
#pragma unroll
    for (int i = 0; i < 4; ++i)
#pragma unroll
      for (int j = 0; j < 4; ++j)
#pragma unroll
        for (int r = 0; r < 4; ++r) {
          int m = bm * 128 + wr * 64 + i * 16 + quad * 4 + r;   // token
          int nn = bn * 128 + wc * 64 + j * 16 + lm;            // feature
          int b = m >> 11, s = m & 2047, h = nn >> 6, d = nn & 63;
          outp[((b * 16 + h) * 2048 + s) * 64 + d] = f2bf(acc[i][j][r] * scale);
        }
  } else {
    // V: transpose 128x128 tile through LDS (chunk-XOR mask 15), store [B,H,64,S]
    unsigned short* scr = &smem[0][0];      // 32KB scratch = buffer 0
#pragma unroll
    for (int i = 0; i < 4; ++i)
#pragma unroll
      for (int j = 0; j < 4; ++j)
#pragma unroll
        for (int r = 0; r < 4; ++r) {
          int ml = wr * 64 + i * 16 + quad * 4 + r;   // token (col of scratch)
          int nl = wc * 64 + j * 16 + lm;             // feature (row of scratch)
          scr[nl * 128 + (((ml >> 3) ^ (nl & 15)) << 3) + (ml & 7)] =
              f2bf(acc[i][j][r]);
        }
    __syncthreads();
    int nl = t >> 1, half = t & 1;
    int e = bn * 128 + nl, h = e >> 6, d = e & 63;
    int mg = bm * 128;
    int b = mg >> 11, s0 = mg & 2047;
    uint4* dstp = (uint4*)(outp + ((b * 16 + h) * 64 + d) * 2048 + s0);
#pragma unroll
    for (int u = 0; u < 8; ++u) {
      int c = half * 8 + u;                 // token chunk 0..15
      int slot = c ^ (nl & 15);
      dstp[c] = *(const uint4*)(scr + nl * 128 + slot * 8);
    }
  }
}

// ---------- flash attention ----------
// Q[B,H,S,64] (pre-scaled by 0.125*log2e), K[B,H,S,64], V^T[B,H,64,S] -> X[B,S,H,64]
// Q-tile 128 rows, KVBLK=64, dbuf 32KB LDS, 4 blocks/CU (R2).
// R3 note: MfmaUtil 45.5 + VALUBusy 46.1 ~= 92% -- pipes sum, not overlap;
// kernel is at ~920 TF effective (plain-HIP attn reference level). This
// round: VALU trims only (kt unroll-by-2 -> static LDS bases; staging
// offsets hoisted out of the loop).
// grid (8,16,8): bh=(x<<3)|z, qt=y -> linear%8 = x: each XCD owns heads
// 8x..8x+7 exclusively; hot K/V per XCD = 4MB = L2.
// K/V double-buffered: stage tile kt+1 before computing kt, ONE barrier/iter.
// S^T = K.Q^T with permuted K rows so P exits in the 16x16x32 A-operand layout.
// Direct exp2 (softmax shift-invariance; scores can't overflow fp32).
// Row-sum l via ones-column MFMA (lacc) instead of VALU adds + end shuffles.
__global__ __launch_bounds__(256, 4) void flash_attn(
    const unsigned short* __restrict__ Qw, const unsigned short* __restrict__ Kw,
    const unsigned short* __restrict__ Vt, unsigned short* __restrict__ Xw) {
  __shared__ __align__(16) unsigned short sK[2][64 * 64];  // 2x8KB, swizzled s(r)
  __shared__ __align__(16) unsigned short sV[2][64 * 64];  // 2x8KB, [d][k], ^(row&7)
  const int t = threadIdx.x;
  const int bh = (blockIdx.x << 3) | blockIdx.z;
  const int qt = blockIdx.y;                 // 0..15, 128-row Q tile
  const int lane = t & 63, lm = lane & 15, quad = lane >> 4;
  const int w = t >> 6;

  const unsigned short* gq = Qw + (long)bh * SEQ * 64 + (long)qt * 128 * 64;
  const unsigned short* gk = Kw + (long)bh * SEQ * 64;
  const unsigned short* gv = Vt + (long)bh * 64 * SEQ;

  // Q fragments straight from global (one-time, 64B/lane)
  bf16x8 qf[2][2];
#pragma unroll
  for (int i = 0; i < 2; ++i)
#pragma unroll
    for (int kc = 0; kc < 2; ++kc)
      qf[i][kc] = *(const bf16x8*)(gq + (w * 32 + i * 16 + lm) * 64 + kc * 32 + quad * 8);

  f32x4 o[2][4];
  f32x4 lacc[2];
#pragma unroll
  for (int i = 0; i < 2; ++i) {
    lacc[i] = (f32x4){0.f, 0.f, 0.f, 0.f};
#pragma unroll
    for (int nv = 0; nv < 4; ++nv) o[i][nv] = (f32x4){0.f, 0.f, 0.f, 0.f};
  }

  // staging offsets hoisted (kt-invariant): 2 K chunks + 2 V chunks per thread
  const int cid0 = t, cid1 = 256 + t;
  const int rk0 = cid0 >> 3, ck0 = cid0 & 7;
  const int rk1 = cid1 >> 3, ck1 = cid1 & 7;
  const int kof0 = rk0 * 64 + (((ck0 ^ ((rk0 & 3) | ((rk0 & 8) >> 1)))) * 8);
  const int kof1 = rk1 * 64 + (((ck1 ^ ((rk1 & 3) | ((rk1 & 8) >> 1)))) * 8);
  const int vof0 = rk0 * SEQ + ((ck0 ^ (rk0 & 7)) * 8);
  const int vof1 = rk1 * SEQ + ((ck1 ^ (rk1 & 7)) * 8);

  auto stage = [&](int kt, int b) {
    gl_lds16(gk + kt * 64 * 64 + kof0, &sK[b][cid0 * 8]);
    gl_lds16(gk + kt * 64 * 64 + kof1, &sK[b][cid1 * 8]);
    gl_lds16(gv + kt * 64 + vof0, &sV[b][cid0 * 8]);
    gl_lds16(gv + kt * 64 + vof1, &sV[b][cid1 * 8]);
  };

  uint4 ou; ou.x = ou.y = ou.z = ou.w = 0x3F803F80u;   // bf16 1.0 x8
  const bf16x8 ones = __builtin_bit_cast(bf16x8, ou);

  stage(0, 0);
  __syncthreads();

#pragma unroll 2
  for (int kt = 0; kt < 32; ++kt) {
    const int cur = kt & 1;
    if (kt < 31) stage(kt + 1, cur ^ 1);   // prefetch: latency hides under compute
    const unsigned short* sk = &sK[cur][0];
    const unsigned short* sv = &sV[cur][0];
#pragma unroll
    for (int p = 0; p < 2; ++p) {
      // permuted K-row fragment reads (A-operand of S^T), shared by both i
      bf16x8 kf[2][2];
#pragma unroll
      for (int tt = 0; tt < 2; ++tt) {
        int g = p * 32 + 8 * (lm >> 2) + (lm & 3) + 4 * tt;
        int sg = (g & 3) | ((g & 8) >> 1);
        kf[tt][0] = *(const bf16x8*)(sk + g * 64 + ((quad ^ sg) * 8));
        kf[tt][1] = *(const bf16x8*)(sk + g * 64 + (((4 + quad) ^ sg) * 8));
      }
      bf16x8 pfrag[2];
#pragma unroll
      for (int i = 0; i < 2; ++i) {
        f32x4 s0 = (f32x4){0.f, 0.f, 0.f, 0.f};
        f32x4 s1 = (f32x4){0.f, 0.f, 0.f, 0.f};
        __builtin_amdgcn_s_setprio(1);
        s0 = mfma16(kf[0][0], qf[i][0], s0);
        s0 = mfma16(kf[0][1], qf[i][1], s0);
        s1 = mfma16(kf[1][0], qf[i][0], s1);
        s1 = mfma16(kf[1][1], qf[i][1], s1);
        __builtin_amdgcn_s_setprio(0);
        float p0[4], p1[4];
#pragma unroll
        for (int r = 0; r < 4; ++r) {
          p0[r] = __builtin_amdgcn_exp2f(s0[r]);
          p1[r] = __builtin_amdgcn_exp2f(s1[r]);
        }
        uint4 pw;
        pw.x = pkbf_t(p0[0], p0[1]); pw.y = pkbf_t(p0[2], p0[3]);
        pw.z = pkbf_t(p1[0], p1[1]); pw.w = pkbf_t(p1[2], p1[3]);
        pfrag[i] = __builtin_bit_cast(bf16x8, pw);
      }
      // PV: o[q][d] += P[q][k]*V[k][d]; l row-sums via ones column
      __builtin_amdgcn_s_setprio(1);
#pragma unroll
      for (int i = 0; i < 2; ++i) lacc[i] = mfma16(pfrag[i], ones, lacc[i]);
#pragma unroll
      for (int nv = 0; nv < 4; ++nv) {
        bf16x8 vb = *(const bf16x8*)(sv + (nv * 16 + lm) * 64 + (((p * 4 + quad) ^ (lm & 7)) * 8));
#pragma unroll
        for (int i = 0; i < 2; ++i) o[i][nv] = mfma16(pfrag[i], vb, o[i][nv]);
      }
      __builtin_amdgcn_s_setprio(0);
    }
    __syncthreads();   // drains this iter's prefetch (vmcnt) + LDS reads
  }

  int b = bh >> 4, h = bh & 15;
#pragma unroll
  for (int i = 0; i < 2; ++i) {
    float inv[4];
#pragma unroll
    for (int r = 0; r < 4; ++r) inv[r] = __builtin_amdgcn_rcpf(lacc[i][r]);
#pragma unroll
    for (int nv = 0; nv < 4; ++nv)
#pragma unroll
      for (int r = 0; r < 4; ++r) {
        int q = qt * 128 + w * 32 + i * 16 + quad * 4 + r;
        int d = nv * 16 + lm;
        Xw[((long)(b * 2048 + q) * 16 + h) * 64 + d] = f2bf(o[i][nv][r] * inv[r]);
      }
  }
}

// ---------- output GEMM: out = X @ Wo^T (pure bf16, fp32 out, BK=64) ----------
// Same double-buffered 2-phase schedule as proj_gemm (bf16 A via gl_lds).
__global__ __launch_bounds__(256, 2) void out_gemm(
    const unsigned short* __restrict__ A, const unsigned short* __restrict__ Bw,
    float* __restrict__ C) {
  __shared__ __align__(16) unsigned short smem[2][16384]; // 64KB
  const int t = threadIdx.x;
  const int bm = blockIdx.x, bn = blockIdx.y;
  const int lane = t & 63, lm = lane & 15, quad = lane >> 4;
  const int w = t >> 6, wr = w >> 1, wc = w & 1;

  f32x4 acc[4][4];
#pragma unroll
  for (int i = 0; i < 4; ++i)
#pragma unroll
    for (int j = 0; j < 4; ++j) acc[i][j] = (f32x4){0.f, 0.f, 0.f, 0.f};

  auto stage = [&](int kk, int b) {
#pragma unroll
    for (int jj = 0; jj < 4; ++jj) {
      int cid = jj * 256 + t;
      int r = cid >> 3, c = cid & 7;
      int gcol = kk * 64 + ((c ^ (r & 7)) * 8);
      gl_lds16(A + (bm * 128 + r) * 1024 + gcol, &smem[b][cid * 8]);
      gl_lds16(Bw + (bn * 128 + r) * 1024 + gcol, &smem[b][8192 + cid * 8]);
    }
  };

  stage(0, 0);
  __syncthreads();

  for (int kk = 0; kk < 16; ++kk) {
    const int cur = kk & 1;
    if (kk < 15) stage(kk + 1, cur ^ 1);   // prefetch: latency hides under compute
    const unsigned short* sA = &smem[cur][0];
    const unsigned short* sB = &smem[cur][8192];
#pragma unroll
    for (int kc = 0; kc < 2; ++kc) {
      bf16x8 af[4], bf[4];
#pragma unroll
      for (int i = 0; i < 4; ++i) {
        int m = wr * 64 + i * 16 + lm;
        int nn = wc * 64 + i * 16 + lm;
        int slot = ((kc * 4 + quad) ^ (lm & 7)) * 8;
        af[i] = *(const bf16x8*)(sA + m * 64 + slot);
        bf[i] = *(const bf16x8*)(sB + nn * 64 + slot);
      }
#pragma unroll
      for (int i = 0; i < 4; ++i)
#pragma unroll
        for (int j = 0; j < 4; ++j) acc[i][j] = mfma16(af[i], bf[j], acc[i][j]);
    }
    __syncthreads();
  }
#pragma unroll
  for (int i = 0; i < 4; ++i)
#pragma unroll
    for (int j = 0; j < 4; ++j)
#pragma unroll
      for (int r = 0; r < 4; ++r) {
        int m = bm * 128 + wr * 64 + i * 16 + quad * 4 + r;
        int nn = bn * 128 + wc * 64 + j * 16 + lm;
        C[m * 1024 + nn] = acc[i][j][r];
      }
}

extern "C" void kernel_launch(void* const* d_in, const int* in_sizes, int n_in,
                              void* d_out, int out_size, void* d_ws, size_t ws_size,
                              hipStream_t stream) {
  const float* q  = (const float*)d_in[0];
  const float* k  = (const float*)d_in[1];
  const float* v  = (const float*)d_in[2];
  const float* Wq = (const float*)d_in[3];
  const float* Wk = (const float*)d_in[4];
  const float* Wv = (const float*)d_in[5];
  const float* Wo = (const float*)d_in[6];

  char* ws = (char*)d_ws;
  const size_t MK = (size_t)MROWS * DMODEL;   // 8,388,608 elems
  const size_t KK = (size_t)DMODEL * DMODEL;  // 1,048,576 elems
  size_t off = 0;
  auto nxt = [&](size_t elems) { unsigned short* p = (unsigned short*)(ws + off); off += elems * 2; return p; };
  unsigned short* Wq_b = nxt(KK);
  unsigned short* Wk_b = nxt(KK);
  unsigned short* Wv_b = nxt(KK);
  unsigned short* Wo_b = nxt(KK);
  unsigned short* Qw = nxt(MK);
  unsigned short* Kw = nxt(MK);
  unsigned short* Vt = nxt(MK);
  unsigned short* Xw = nxt(MK);
  (void)ws_size; (void)in_sizes; (void)n_in; (void)out_size;

  // 4*262144 float4-groups / 256 = 4096 blocks exactly
  cvt_w<<<4096, 256, 0, stream>>>(Wq, Wk, Wv, Wo, Wq_b, Wk_b, Wv_b, Wo_b);
  proj_gemm<<<dim3(64, 8, 3), 256, 0, stream>>>(q, k, v,
                                                Wq_b, Wk_b, Wv_b,
                                                Qw, Kw, Vt);
  flash_attn<<<dim3(8, 16, 8), 256, 0, stream>>>(Qw, Kw, Vt, Xw);
  out_gemm<<<dim3(64, 8), 256, 0, stream>>>(Xw, Wo_b, (float*)d_out);
}

// Round 5
// 297.676 us; speedup vs baseline: 1.1757x; 1.1757x over previous
//
#include <hip/hip_runtime.h>
#include <stdint.h>

#define NHEAD 16
#define DKH 64
#define BBATCH 4
#define SEQ 2048
#define MROWS (BBATCH*SEQ)   // 8192
#define DMODEL 1024

typedef __attribute__((ext_vector_type(8))) __bf16 bf16x8;
typedef __attribute__((ext_vector_type(4))) float f32x4;

__device__ __forceinline__ unsigned short f2bf(float x) {
  unsigned int u = __float_as_uint(x);
  u += 0x7FFFu + ((u >> 16) & 1u);          // RN-even
  return (unsigned short)(u >> 16);
}
// pack bf16(a) | bf16(b)<<16, round-half-up: 2 adds + 1 v_perm
__device__ __forceinline__ unsigned int pkbf(float a, float b) {
  return __builtin_amdgcn_perm(__float_as_uint(b) + 0x8000u,
                               __float_as_uint(a) + 0x8000u, 0x07060302u);
}
// truncating pack (1 v_perm). Used only for P: downward bias cancels in
// softmax normalization because l (ones-MFMA) sums the same truncated values.
__device__ __forceinline__ unsigned int pkbf_t(float a, float b) {
  return __builtin_amdgcn_perm(__float_as_uint(b), __float_as_uint(a), 0x07060302u);
}
__device__ __forceinline__ void gl_lds16(const void* g, void* l) {
  __builtin_amdgcn_global_load_lds(
      (const __attribute__((address_space(1))) unsigned int*)g,
      (__attribute__((address_space(3))) unsigned int*)l, 16, 0, 0);
}
__device__ __forceinline__ f32x4 mfma16(bf16x8 a, bf16x8 b, f32x4 c) {
  return __builtin_amdgcn_mfma_f32_16x16x32_bf16(a, b, c, 0, 0, 0);
}

// ---------- fused fp32 -> bf16 convert for all 7 tensors ----------
// R4 lesson: fusing q/k/v cvt into proj's staging (reg-staged fp32 A)
// regressed proj 62->147us (2x global bytes + ds_write chain on the
// critical path, no TLP at 2 blocks/CU). global_load_lds staging requires
// bf16 already in memory -> keep the separate full-width cvt pass.
__global__ __launch_bounds__(256) void cvt_all(
    const float* __restrict__ s0, const float* __restrict__ s1,
    const float* __restrict__ s2, const float* __restrict__ s3,
    const float* __restrict__ s4, const float* __restrict__ s5,
    const float* __restrict__ s6,
    unsigned short* __restrict__ d0, unsigned short* __restrict__ d1,
    unsigned short* __restrict__ d2, unsigned short* __restrict__ d3,
    unsigned short* __restrict__ d4, unsigned short* __restrict__ d5,
    unsigned short* __restrict__ d6) {
  const int NB = 2097152;   // float4 groups in q/k/v
  const int NW = 262144;    // float4 groups in each W
  int i = blockIdx.x * 256 + threadIdx.x;
  const float* src; unsigned short* dst; int off;
  if      (i < NB)          { src = s0; dst = d0; off = i; }
  else if (i < 2*NB)        { src = s1; dst = d1; off = i - NB; }
  else if (i < 3*NB)        { src = s2; dst = d2; off = i - 2*NB; }
  else if (i < 3*NB + NW)   { src = s3; dst = d3; off = i - 3*NB; }
  else if (i < 3*NB + 2*NW) { src = s4; dst = d4; off = i - 3*NB - NW; }
  else if (i < 3*NB + 3*NW) { src = s5; dst = d5; off = i - 3*NB - 2*NW; }
  else                      { src = s6; dst = d6; off = i - 3*NB - 3*NW; }
  float4 x = ((const float4*)src)[off];
  uint2 o; o.x = pkbf(x.x, x.y); o.y = pkbf(x.z, x.w);
  ((uint2*)dst)[off] = o;
}

// ---------- fused Q/K/V projection GEMM: Y = X @ W^T (pure bf16) ----------
// BK=64, double-buffered (2x32KB LDS): stage tile kk+1 BEFORE computing kk,
// ONE barrier/iter -> global_load_lds latency hides under 32 MFMA + 16
// ds_read of the current tile.
// LDS rows of 64 elems, 8 chunks of 8; slot s of row r holds source chunk
// s ^ (r&7) -> conflict-free staging AND fragment reads.
// z=0: Q -> [B,H,S,64] scaled by 0.125*log2e; z=1: K; z=2: V^T [B,H,64,S].
__global__ __launch_bounds__(256, 2) void proj_gemm(
    const unsigned short* __restrict__ A0, const unsigned short* __restrict__ A1,
    const unsigned short* __restrict__ A2,
    const unsigned short* __restrict__ B0, const unsigned short* __restrict__ B1,
    const unsigned short* __restrict__ B2,
    unsigned short* __restrict__ O0, unsigned short* __restrict__ O1,
    unsigned short* __restrict__ O2) {
  // [buf][ A: 0..8191 | B: 8192..16383 ]; buf0 doubles as transpose scratch (z=2)
  __shared__ __align__(16) unsigned short smem[2][16384]; // 64KB
  const int z = blockIdx.z;
  const unsigned short* Ah = (z == 0) ? A0 : ((z == 1) ? A1 : A2);
  const unsigned short* Bh = (z == 0) ? B0 : ((z == 1) ? B1 : B2);
  unsigned short* outp = (z == 0) ? O0 : ((z == 1) ? O1 : O2);
  const int t = threadIdx.x;
  const int bm = blockIdx.x, bn = blockIdx.y;
  const int lane = t & 63, lm = lane & 15, quad = lane >> 4;
  const int w = t >> 6, wr = w >> 1, wc = w & 1;

  f32x4 acc[4][4];
#pragma unroll
  for (int i = 0; i < 4; ++i)
#pragma unroll
    for (int j = 0; j < 4; ++j) acc[i][j] = (f32x4){0.f, 0.f, 0.f, 0.f};

  auto stage = [&](int kk, int b) {
#pragma unroll
    for (int jj = 0; jj < 4; ++jj) {
      int cid = jj * 256 + t;              // 0..1023
      int r = cid >> 3, c = cid & 7;
      int gcol = kk * 64 + ((c ^ (r & 7)) * 8);
      gl_lds16(Ah + (bm * 128 + r) * 1024 + gcol, &smem[b][cid * 8]);
      gl_lds16(Bh + (bn * 128 + r) * 1024 + gcol, &smem[b][8192 + cid * 8]);
    }
  };

  stage(0, 0);
  __syncthreads();

  for (int kk = 0; kk < 16; ++kk) {
    const int cur = kk & 1;
    if (kk < 15) stage(kk + 1, cur ^ 1);   // prefetch: latency hides under compute
    const unsigned short* sA = &smem[cur][0];
    const unsigned short* sB = &smem[cur][8192];
#pragma unroll
    for (int kc = 0; kc < 2; ++kc) {
      bf16x8 af[4], bf[4];
#pragma unroll
      for (int i = 0; i < 4; ++i) {
        int m = wr * 64 + i * 16 + lm;
        int nn = wc * 64 + i * 16 + lm;
        int slot = ((kc * 4 + quad) ^ (lm & 7)) * 8;
        af[i] = *(const bf16x8*)(sA + m * 64 + slot);
        bf[i] = *(const bf16x8*)(sB + nn * 64 + slot);
      }
#pragma unroll
      for (int i = 0; i < 4; ++i)
#pragma unroll
        for (int j = 0; j < 4; ++j) acc[i][j] = mfma16(af[i], bf[j], acc[i][j]);
    }
    __syncthreads();   // drains this iter's prefetch (vmcnt) + LDS reads
  }

  if (z < 2) {
    float scale = (z == 0) ? 0.125f * 1.44269504f : 1.0f;
#pragma unroll
    for (int i = 0; i < 4; ++i)
#pragma unroll
      for (int j = 0; j < 4; ++j)
#pragma unroll
        for (int r = 0; r < 4; ++r) {
          int m = bm * 128 + wr * 64 + i * 16 + quad * 4 + r;   // token
          int nn = bn * 128 + wc * 64 + j * 16 + lm;            // feature
          int b = m >> 11, s = m & 2047, h = nn >> 6, d = nn & 63;
          outp[((b * 16 + h) * 2048 + s) * 64 + d] = f2bf(acc[i][j][r] * scale);
        }
  } else {
    // V: transpose 128x128 tile through LDS (chunk-XOR mask 15), store [B,H,64,S]
    unsigned short* scr = &smem[0][0];      // 32KB scratch = buffer 0
#pragma unroll
    for (int i = 0; i < 4; ++i)
#pragma unroll
      for (int j = 0; j < 4; ++j)
#pragma unroll
        for (int r = 0; r < 4; ++r) {
          int ml = wr * 64 + i * 16 + quad * 4 + r;   // token (col of scratch)
          int nl = wc * 64 + j * 16 + lm;             // feature (row of scratch)
          scr[nl * 128 + (((ml >> 3) ^ (nl & 15)) << 3) + (ml & 7)] =
              f2bf(acc[i][j][r]);
        }
    __syncthreads();
    int nl = t >> 1, half = t & 1;
    int e = bn * 128 + nl, h = e >> 6, d = e & 63;
    int mg = bm * 128;
    int b = mg >> 11, s0 = mg & 2047;
    uint4* dstp = (uint4*)(outp + ((b * 16 + h) * 64 + d) * 2048 + s0);
#pragma unroll
    for (int u = 0; u < 8; ++u) {
      int c = half * 8 + u;                 // token chunk 0..15
      int slot = c ^ (nl & 15);
      dstp[c] = *(const uint4*)(scr + nl * 128 + slot * 8);
    }
  }
}

// ---------- flash attention ----------
// Q[B,H,S,64] (pre-scaled by 0.125*log2e), K[B,H,S,64], V^T[B,H,64,S] -> X[B,S,H,64]
// Q-tile 128 rows, KVBLK=64, dbuf 32KB LDS, 4 blocks/CU (R2 config, 74.6us,
// MfmaUtil 45.5 + VALUBusy 46.1 ~= 92%: pipe-sum saturated, ~920 TF eff).
// R3 micro-tweaks kept: hoisted staging offsets, kt unroll-2 (static bases).
// grid (8,16,8): bh=(x<<3)|z, qt=y -> linear%8 = x: each XCD owns heads
// 8x..8x+7 exclusively; hot K/V per XCD = 4MB = L2.
// K/V double-buffered: stage tile kt+1 before computing kt, ONE barrier/iter.
// S^T = K.Q^T with permuted K rows so P exits in the 16x16x32 A-operand layout.
// Direct exp2 (softmax shift-invariance; scores can't overflow fp32).
// Row-sum l via ones-column MFMA (lacc) instead of VALU adds + end shuffles.
__global__ __launch_bounds__(256, 4) void flash_attn(
    const unsigned short* __restrict__ Qw, const unsigned short* __restrict__ Kw,
    const unsigned short* __restrict__ Vt, unsigned short* __restrict__ Xw) {
  __shared__ __align__(16) unsigned short sK[2][64 * 64];  // 2x8KB, swizzled s(r)
  __shared__ __align__(16) unsigned short sV[2][64 * 64];  // 2x8KB, [d][k], ^(row&7)
  const int t = threadIdx.x;
  const int bh = (blockIdx.x << 3) | blockIdx.z;
  const int qt = blockIdx.y;                 // 0..15, 128-row Q tile
  const int lane = t & 63, lm = lane & 15, quad = lane >> 4;
  const int w = t >> 6;

  const unsigned short* gq = Qw + (long)bh * SEQ * 64 + (long)qt * 128 * 64;
  const unsigned short* gk = Kw + (long)bh * SEQ * 64;
  const unsigned short* gv = Vt + (long)bh * 64 * SEQ;

  // Q fragments straight from global (one-time, 64B/lane)
  bf16x8 qf[2][2];
#pragma unroll
  for (int i = 0; i < 2; ++i)
#pragma unroll
    for (int kc = 0; kc < 2; ++kc)
      qf[i][kc] = *(const bf16x8*)(gq + (w * 32 + i * 16 + lm) * 64 + kc * 32 + quad * 8);

  f32x4 o[2][4];
  f32x4 lacc[2];
#pragma unroll
  for (int i = 0; i < 2; ++i) {
    lacc[i] = (f32x4){0.f, 0.f, 0.f, 0.f};
#pragma unroll
    for (int nv = 0; nv < 4; ++nv) o[i][nv] = (f32x4){0.f, 0.f, 0.f, 0.f};
  }

  // staging offsets hoisted (kt-invariant): 2 K chunks + 2 V chunks per thread
  const int cid0 = t, cid1 = 256 + t;
  const int rk0 = cid0 >> 3, ck0 = cid0 & 7;
  const int rk1 = cid1 >> 3, ck1 = cid1 & 7;
  const int kof0 = rk0 * 64 + (((ck0 ^ ((rk0 & 3) | ((rk0 & 8) >> 1)))) * 8);
  const int kof1 = rk1 * 64 + (((ck1 ^ ((rk1 & 3) | ((rk1 & 8) >> 1)))) * 8);
  const int vof0 = rk0 * SEQ + ((ck0 ^ (rk0 & 7)) * 8);
  const int vof1 = rk1 * SEQ + ((ck1 ^ (rk1 & 7)) * 8);

  auto stage = [&](int kt, int b) {
    gl_lds16(gk + kt * 64 * 64 + kof0, &sK[b][cid0 * 8]);
    gl_lds16(gk + kt * 64 * 64 + kof1, &sK[b][cid1 * 8]);
    gl_lds16(gv + kt * 64 + vof0, &sV[b][cid0 * 8]);
    gl_lds16(gv + kt * 64 + vof1, &sV[b][cid1 * 8]);
  };

  uint4 ou; ou.x = ou.y = ou.z = ou.w = 0x3F803F80u;   // bf16 1.0 x8
  const bf16x8 ones = __builtin_bit_cast(bf16x8, ou);

  stage(0, 0);
  __syncthreads();

#pragma unroll 2
  for (int kt = 0; kt < 32; ++kt) {
    const int cur = kt & 1;
    if (kt < 31) stage(kt + 1, cur ^ 1);   // prefetch: latency hides under compute
    const unsigned short* sk = &sK[cur][0];
    const unsigned short* sv = &sV[cur][0];
#pragma unroll
    for (int p = 0; p < 2; ++p) {
      // permuted K-row fragment reads (A-operand of S^T), shared by both i
      bf16x8 kf[2][2];
#pragma unroll
      for (int tt = 0; tt < 2; ++tt) {
        int g = p * 32 + 8 * (lm >> 2) + (lm & 3) + 4 * tt;
        int sg = (g & 3) | ((g & 8) >> 1);
        kf[tt][0] = *(const bf16x8*)(sk + g * 64 + ((quad ^ sg) * 8));
        kf[tt][1] = *(const bf16x8*)(sk + g * 64 + (((4 + quad) ^ sg) * 8));
      }
      bf16x8 pfrag[2];
#pragma unroll
      for (int i = 0; i < 2; ++i) {
        f32x4 s0 = (f32x4){0.f, 0.f, 0.f, 0.f};
        f32x4 s1 = (f32x4){0.f, 0.f, 0.f, 0.f};
        __builtin_amdgcn_s_setprio(1);
        s0 = mfma16(kf[0][0], qf[i][0], s0);
        s0 = mfma16(kf[0][1], qf[i][1], s0);
        s1 = mfma16(kf[1][0], qf[i][0], s1);
        s1 = mfma16(kf[1][1], qf[i][1], s1);
        __builtin_amdgcn_s_setprio(0);
        float p0[4], p1[4];
#pragma unroll
        for (int r = 0; r < 4; ++r) {
          p0[r] = __builtin_amdgcn_exp2f(s0[r]);
          p1[r] = __builtin_amdgcn_exp2f(s1[r]);
        }
        uint4 pw;
        pw.x = pkbf_t(p0[0], p0[1]); pw.y = pkbf_t(p0[2], p0[3]);
        pw.z = pkbf_t(p1[0], p1[1]); pw.w = pkbf_t(p1[2], p1[3]);
        pfrag[i] = __builtin_bit_cast(bf16x8, pw);
      }
      // PV: o[q][d] += P[q][k]*V[k][d]; l row-sums via ones column
      __builtin_amdgcn_s_setprio(1);
#pragma unroll
      for (int i = 0; i < 2; ++i) lacc[i] = mfma16(pfrag[i], ones, lacc[i]);
#pragma unroll
      for (int nv = 0; nv < 4; ++nv) {
        bf16x8 vb = *(const bf16x8*)(sv + (nv * 16 + lm) * 64 + (((p * 4 + quad) ^ (lm & 7)) * 8));
#pragma unroll
        for (int i = 0; i < 2; ++i) o[i][nv] = mfma16(pfrag[i], vb, o[i][nv]);
      }
      __builtin_amdgcn_s_setprio(0);
    }
    __syncthreads();   // drains this iter's prefetch (vmcnt) + LDS reads
  }

  int b = bh >> 4, h = bh & 15;
#pragma unroll
  for (int i = 0; i < 2; ++i) {
    float inv[4];
#pragma unroll
    for (int r = 0; r < 4; ++r) inv[r] = __builtin_amdgcn_rcpf(lacc[i][r]);
#pragma unroll
    for (int nv = 0; nv < 4; ++nv)
#pragma unroll
      for (int r = 0; r < 4; ++r) {
        int q = qt * 128 + w * 32 + i * 16 + quad * 4 + r;
        int d = nv * 16 + lm;
        Xw[((long)(b * 2048 + q) * 16 + h) * 64 + d] = f2bf(o[i][nv][r] * inv[r]);
      }
  }
}

// ---------- output GEMM: out = X @ Wo^T (pure bf16, fp32 out, BK=64) ----------
// Same double-buffered 2-phase schedule as proj_gemm.
__global__ __launch_bounds__(256, 2) void out_gemm(
    const unsigned short* __restrict__ A, const unsigned short* __restrict__ Bw,
    float* __restrict__ C) {
  __shared__ __align__(16) unsigned short smem[2][16384]; // 64KB
  const int t = threadIdx.x;
  const int bm = blockIdx.x, bn = blockIdx.y;
  const int lane = t & 63, lm = lane & 15, quad = lane >> 4;
  const int w = t >> 6, wr = w >> 1, wc = w & 1;

  f32x4 acc[4][4];
#pragma unroll
  for (int i = 0; i < 4; ++i)
#pragma unroll
    for (int j = 0; j < 4; ++j) acc[i][j] = (f32x4){0.f, 0.f, 0.f, 0.f};

  auto stage = [&](int kk, int b) {
#pragma unroll
    for (int jj = 0; jj < 4; ++jj) {
      int cid = jj * 256 + t;
      int r = cid >> 3, c = cid & 7;
      int gcol = kk * 64 + ((c ^ (r & 7)) * 8);
      gl_lds16(A + (bm * 128 + r) * 1024 + gcol, &smem[b][cid * 8]);
      gl_lds16(Bw + (bn * 128 + r) * 1024 + gcol, &smem[b][8192 + cid * 8]);
    }
  };

  stage(0, 0);
  __syncthreads();

  for (int kk = 0; kk < 16; ++kk) {
    const int cur = kk & 1;
    if (kk < 15) stage(kk + 1, cur ^ 1);   // prefetch: latency hides under compute
    const unsigned short* sA = &smem[cur][0];
    const unsigned short* sB = &smem[cur][8192];
#pragma unroll
    for (int kc = 0; kc < 2; ++kc) {
      bf16x8 af[4], bf[4];
#pragma unroll
      for (int i = 0; i < 4; ++i) {
        int m = wr * 64 + i * 16 + lm;
        int nn = wc * 64 + i * 16 + lm;
        int slot = ((kc * 4 + quad) ^ (lm & 7)) * 8;
        af[i] = *(const bf16x8*)(sA + m * 64 + slot);
        bf[i] = *(const bf16x8*)(sB + nn * 64 + slot);
      }
#pragma unroll
      for (int i = 0; i < 4; ++i)
#pragma unroll
        for (int j = 0; j < 4; ++j) acc[i][j] = mfma16(af[i], bf[j], acc[i][j]);
    }
    __syncthreads();
  }
#pragma unroll
  for (int i = 0; i < 4; ++i)
#pragma unroll
    for (int j = 0; j < 4; ++j)
#pragma unroll
      for (int r = 0; r < 4; ++r) {
        int m = bm * 128 + wr * 64 + i * 16 + quad * 4 + r;
        int nn = bn * 128 + wc * 64 + j * 16 + lm;
        C[m * 1024 + nn] = acc[i][j][r];
      }
}

extern "C" void kernel_launch(void* const* d_in, const int* in_sizes, int n_in,
                              void* d_out, int out_size, void* d_ws, size_t ws_size,
                              hipStream_t stream) {
  const float* q  = (const float*)d_in[0];
  const float* k  = (const float*)d_in[1];
  const float* v  = (const float*)d_in[2];
  const float* Wq = (const float*)d_in[3];
  const float* Wk = (const float*)d_in[4];
  const float* Wv = (const float*)d_in[5];
  const float* Wo = (const float*)d_in[6];

  char* ws = (char*)d_ws;
  const size_t MK = (size_t)MROWS * DMODEL;   // 8,388,608 elems
  const size_t KK = (size_t)DMODEL * DMODEL;  // 1,048,576 elems
  size_t off = 0;
  auto nxt = [&](size_t elems) { unsigned short* p = (unsigned short*)(ws + off); off += elems * 2; return p; };
  unsigned short* q_b  = nxt(MK);
  unsigned short* k_b  = nxt(MK);
  unsigned short* v_b  = nxt(MK);
  unsigned short* Wq_b = nxt(KK);
  unsigned short* Wk_b = nxt(KK);
  unsigned short* Wv_b = nxt(KK);
  unsigned short* Wo_b = nxt(KK);
  unsigned short* Qw = nxt(MK);
  unsigned short* Kw = nxt(MK);
  unsigned short* Vt = nxt(MK);
  unsigned short* Xw = nxt(MK);
  (void)ws_size; (void)in_sizes; (void)n_in; (void)out_size;

  // (3*2097152 + 4*262144) float4-groups / 256 = 28672 blocks exactly
  cvt_all<<<28672, 256, 0, stream>>>(q, k, v, Wq, Wk, Wv, Wo,
                                     q_b, k_b, v_b, Wq_b, Wk_b, Wv_b, Wo_b);
  proj_gemm<<<dim3(64, 8, 3), 256, 0, stream>>>(q_b, k_b, v_b,
                                                Wq_b, Wk_b, Wv_b,
                                                Qw, Kw, Vt);
  flash_attn<<<dim3(8, 16, 8), 256, 0, stream>>>(Qw, Kw, Vt, Xw);
  out_gemm<<<dim3(64, 8), 256, 0, stream>>>(Xw, Wo_b, (float*)d_out);
}

// Round 6
// 289.282 us; speedup vs baseline: 1.2098x; 1.0290x over previous
//
#include <hip/hip_runtime.h>
#include <stdint.h>

#define NHEAD 16
#define DKH 64
#define BBATCH 4
#define SEQ 2048
#define MROWS (BBATCH*SEQ)   // 8192
#define DMODEL 1024

typedef __attribute__((ext_vector_type(8))) __bf16 bf16x8;
typedef __attribute__((ext_vector_type(4))) float f32x4;

__device__ __forceinline__ unsigned short f2bf(float x) {
  unsigned int u = __float_as_uint(x);
  u += 0x7FFFu + ((u >> 16) & 1u);          // RN-even
  return (unsigned short)(u >> 16);
}
// pack bf16(a) | bf16(b)<<16, round-half-up: 2 adds + 1 v_perm
__device__ __forceinline__ unsigned int pkbf(float a, float b) {
  return __builtin_amdgcn_perm(__float_as_uint(b) + 0x8000u,
                               __float_as_uint(a) + 0x8000u, 0x07060302u);
}
// truncating pack (1 v_perm). Used only for P: downward bias cancels in
// softmax normalization because l (ones-MFMA) sums the same truncated values.
__device__ __forceinline__ unsigned int pkbf_t(float a, float b) {
  return __builtin_amdgcn_perm(__float_as_uint(b), __float_as_uint(a), 0x07060302u);
}
__device__ __forceinline__ void gl_lds16(const void* g, void* l) {
  __builtin_amdgcn_global_load_lds(
      (const __attribute__((address_space(1))) unsigned int*)g,
      (__attribute__((address_space(3))) unsigned int*)l, 16, 0, 0);
}
__device__ __forceinline__ f32x4 mfma16(bf16x8 a, bf16x8 b, f32x4 c) {
  return __builtin_amdgcn_mfma_f32_16x16x32_bf16(a, b, c, 0, 0, 0);
}

// ---------- fused fp32 -> bf16 convert for all 7 tensors ----------
// R4 lesson: fusing q/k/v cvt into proj's staging (reg-staged fp32 A)
// regressed proj 62->147us (2x global bytes + ds_write chain on the
// critical path, no TLP at 2 blocks/CU). global_load_lds staging requires
// bf16 already in memory -> keep the separate full-width cvt pass.
// 16B loads / 8B stores per lane = within the coalescing sweet spot.
__global__ __launch_bounds__(256) void cvt_all(
    const float* __restrict__ s0, const float* __restrict__ s1,
    const float* __restrict__ s2, const float* __restrict__ s3,
    const float* __restrict__ s4, const float* __restrict__ s5,
    const float* __restrict__ s6,
    unsigned short* __restrict__ d0, unsigned short* __restrict__ d1,
    unsigned short* __restrict__ d2, unsigned short* __restrict__ d3,
    unsigned short* __restrict__ d4, unsigned short* __restrict__ d5,
    unsigned short* __restrict__ d6) {
  const int NB = 2097152;   // float4 groups in q/k/v
  const int NW = 262144;    // float4 groups in each W
  int i = blockIdx.x * 256 + threadIdx.x;
  const float* src; unsigned short* dst; int off;
  if      (i < NB)          { src = s0; dst = d0; off = i; }
  else if (i < 2*NB)        { src = s1; dst = d1; off = i - NB; }
  else if (i < 3*NB)        { src = s2; dst = d2; off = i - 2*NB; }
  else if (i < 3*NB + NW)   { src = s3; dst = d3; off = i - 3*NB; }
  else if (i < 3*NB + 2*NW) { src = s4; dst = d4; off = i - 3*NB - NW; }
  else if (i < 3*NB + 3*NW) { src = s5; dst = d5; off = i - 3*NB - 2*NW; }
  else                      { src = s6; dst = d6; off = i - 3*NB - 3*NW; }
  float4 x = ((const float4*)src)[off];
  uint2 o; o.x = pkbf(x.x, x.y); o.y = pkbf(x.z, x.w);
  ((uint2*)dst)[off] = o;
}

// ---------- fused Q/K/V projection GEMM: Y = X @ W^T (pure bf16) ----------
// BK=64, double-buffered (2x32KB LDS): stage tile kk+1 BEFORE computing kk,
// ONE barrier/iter -> global_load_lds latency hides under 32 MFMA + 16
// ds_read of the current tile.
// LDS rows of 64 elems, 8 chunks of 8; slot s of row r holds source chunk
// s ^ (r&7) -> conflict-free staging AND fragment reads.
// z=0: Q -> [B,H,S,64] scaled by 0.125*log2e; z=1: K; z=2: V^T [B,H,64,S].
__global__ __launch_bounds__(256, 2) void proj_gemm(
    const unsigned short* __restrict__ A0, const unsigned short* __restrict__ A1,
    const unsigned short* __restrict__ A2,
    const unsigned short* __restrict__ B0, const unsigned short* __restrict__ B1,
    const unsigned short* __restrict__ B2,
    unsigned short* __restrict__ O0, unsigned short* __restrict__ O1,
    unsigned short* __restrict__ O2) {
  // [buf][ A: 0..8191 | B: 8192..16383 ]; buf0 doubles as transpose scratch (z=2)
  __shared__ __align__(16) unsigned short smem[2][16384]; // 64KB
  const int z = blockIdx.z;
  const unsigned short* Ah = (z == 0) ? A0 : ((z == 1) ? A1 : A2);
  const unsigned short* Bh = (z == 0) ? B0 : ((z == 1) ? B1 : B2);
  unsigned short* outp = (z == 0) ? O0 : ((z == 1) ? O1 : O2);
  const int t = threadIdx.x;
  const int bm = blockIdx.x, bn = blockIdx.y;
  const int lane = t & 63, lm = lane & 15, quad = lane >> 4;
  const int w = t >> 6, wr = w >> 1, wc = w & 1;

  f32x4 acc[4][4];
#pragma unroll
  for (int i = 0; i < 4; ++i)
#pragma unroll
    for (int j = 0; j < 4; ++j) acc[i][j] = (f32x4){0.f, 0.f, 0.f, 0.f};

  auto stage = [&](int kk, int b) {
#pragma unroll
    for (int jj = 0; jj < 4; ++jj) {
      int cid = jj * 256 + t;              // 0..1023
      int r = cid >> 3, c = cid & 7;
      int gcol = kk * 64 + ((c ^ (r & 7)) * 8);
      gl_lds16(Ah + (bm * 128 + r) * 1024 + gcol, &smem[b][cid * 8]);
      gl_lds16(Bh + (bn * 128 + r) * 1024 + gcol, &smem[b][8192 + cid * 8]);
    }
  };

  stage(0, 0);
  __syncthreads();

  for (int kk = 0; kk < 16; ++kk) {
    const int cur = kk & 1;
    if (kk < 15) stage(kk + 1, cur ^ 1);   // prefetch: latency hides under compute
    const unsigned short* sA = &smem[cur][0];
    const unsigned short* sB = &smem[cur][8192];
#pragma unroll
    for (int kc = 0; kc < 2; ++kc) {
      bf16x8 af[4], bf[4];
#pragma unroll
      for (int i = 0; i < 4; ++i) {
        int m = wr * 64 + i * 16 + lm;
        int nn = wc * 64 + i * 16 + lm;
        int slot = ((kc * 4 + quad) ^ (lm & 7)) * 8;
        af[i] = *(const bf16x8*)(sA + m * 64 + slot);
        bf[i] = *(const bf16x8*)(sB + nn * 64 + slot);
      }
#pragma unroll
      for (int i = 0; i < 4; ++i)
#pragma unroll
        for (int j = 0; j < 4; ++j) acc[i][j] = mfma16(af[i], bf[j], acc[i][j]);
    }
    __syncthreads();   // drains this iter's prefetch (vmcnt) + LDS reads
  }

  if (z < 2) {
    float scale = (z == 0) ? 0.125f * 1.44269504f : 1.0f;
#pragma unroll
    for (int i = 0; i < 4; ++i)
#pragma unroll
      for (int j = 0; j < 4; ++j)
#pragma unroll
        for (int r = 0; r < 4; ++r) {
          int m = bm * 128 + wr * 64 + i * 16 + quad * 4 + r;   // token
          int nn = bn * 128 + wc * 64 + j * 16 + lm;            // feature
          int b = m >> 11, s = m & 2047, h = nn >> 6, d = nn & 63;
          outp[((b * 16 + h) * 2048 + s) * 64 + d] = f2bf(acc[i][j][r] * scale);
        }
  } else {
    // V: transpose 128x128 tile through LDS (chunk-XOR mask 15), store [B,H,64,S]
    unsigned short* scr = &smem[0][0];      // 32KB scratch = buffer 0
#pragma unroll
    for (int i = 0; i < 4; ++i)
#pragma unroll
      for (int j = 0; j < 4; ++j)
#pragma unroll
        for (int r = 0; r < 4; ++r) {
          int ml = wr * 64 + i * 16 + quad * 4 + r;   // token (col of scratch)
          int nl = wc * 64 + j * 16 + lm;             // feature (row of scratch)
          scr[nl * 128 + (((ml >> 3) ^ (nl & 15)) << 3) + (ml & 7)] =
              f2bf(acc[i][j][r]);
        }
    __syncthreads();
    int nl = t >> 1, half = t & 1;
    int e = bn * 128 + nl, h = e >> 6, d = e & 63;
    int mg = bm * 128;
    int b = mg >> 11, s0 = mg & 2047;
    uint4* dstp = (uint4*)(outp + ((b * 16 + h) * 64 + d) * 2048 + s0);
#pragma unroll
    for (int u = 0; u < 8; ++u) {
      int c = half * 8 + u;                 // token chunk 0..15
      int slot = c ^ (nl & 15);
      dstp[c] = *(const uint4*)(scr + nl * 128 + slot * 8);
    }
  }
}

// ---------- flash attention ----------
// Q[B,H,S,64] (pre-scaled by 0.125*log2e), K[B,H,S,64], V^T[B,H,64,S] -> X[B,S,H,64]
// Q-tile 128 rows, KVBLK=64, dbuf 32KB LDS (R2 config).
// R5 restructure (T15-style 2-state pipeline, m214v36): phase A computes
// QK^T MFMAs for BOTH p halves into s[2][..]; phase B does softmax+PV per p.
// Program order then lets exp2/pack(p=1) issue while PV(p=0) MFMAs drain
// (PV(1) depends on PV(0)'s o accumulators; the VALU work covers that MFMA
// chain latency). R2-R5 counters showed MfmaUtil 46 + VALUBusy 44 SUMMED
// (pipes serialized along the per-wave QK->exp2->pack->PV chain).
// Bit-identical numerics: same ops, same per-accumulator order.
// grid (8,16,8): bh=(x<<3)|z, qt=y -> linear%8 = x: each XCD owns heads
// 8x..8x+7 exclusively; hot K/V per XCD = 4MB = L2.
// K/V double-buffered: stage tile kt+1 before computing kt, ONE barrier/iter.
// S^T = K.Q^T with permuted K rows so P exits in the 16x16x32 A-operand layout.
// Direct exp2 (softmax shift-invariance; scores can't overflow fp32).
// Row-sum l via ones-column MFMA (lacc) instead of VALU adds + end shuffles.
__global__ __launch_bounds__(256, 4) void flash_attn(
    const unsigned short* __restrict__ Qw, const unsigned short* __restrict__ Kw,
    const unsigned short* __restrict__ Vt, unsigned short* __restrict__ Xw) {
  __shared__ __align__(16) unsigned short sK[2][64 * 64];  // 2x8KB, swizzled s(r)
  __shared__ __align__(16) unsigned short sV[2][64 * 64];  // 2x8KB, [d][k], ^(row&7)
  const int t = threadIdx.x;
  const int bh = (blockIdx.x << 3) | blockIdx.z;
  const int qt = blockIdx.y;                 // 0..15, 128-row Q tile
  const int lane = t & 63, lm = lane & 15, quad = lane >> 4;
  const int w = t >> 6;

  const unsigned short* gq = Qw + (long)bh * SEQ * 64 + (long)qt * 128 * 64;
  const unsigned short* gk = Kw + (long)bh * SEQ * 64;
  const unsigned short* gv = Vt + (long)bh * 64 * SEQ;

  // Q fragments straight from global (one-time, 64B/lane)
  bf16x8 qf[2][2];
#pragma unroll
  for (int i = 0; i < 2; ++i)
#pragma unroll
    for (int kc = 0; kc < 2; ++kc)
      qf[i][kc] = *(const bf16x8*)(gq + (w * 32 + i * 16 + lm) * 64 + kc * 32 + quad * 8);

  f32x4 o[2][4];
  f32x4 lacc[2];
#pragma unroll
  for (int i = 0; i < 2; ++i) {
    lacc[i] = (f32x4){0.f, 0.f, 0.f, 0.f};
#pragma unroll
    for (int nv = 0; nv < 4; ++nv) o[i][nv] = (f32x4){0.f, 0.f, 0.f, 0.f};
  }

  // staging offsets hoisted (kt-invariant): 2 K chunks + 2 V chunks per thread
  const int cid0 = t, cid1 = 256 + t;
  const int rk0 = cid0 >> 3, ck0 = cid0 & 7;
  const int rk1 = cid1 >> 3, ck1 = cid1 & 7;
  const int kof0 = rk0 * 64 + (((ck0 ^ ((rk0 & 3) | ((rk0 & 8) >> 1)))) * 8);
  const int kof1 = rk1 * 64 + (((ck1 ^ ((rk1 & 3) | ((rk1 & 8) >> 1)))) * 8);
  const int vof0 = rk0 * SEQ + ((ck0 ^ (rk0 & 7)) * 8);
  const int vof1 = rk1 * SEQ + ((ck1 ^ (rk1 & 7)) * 8);

  auto stage = [&](int kt, int b) {
    gl_lds16(gk + kt * 64 * 64 + kof0, &sK[b][cid0 * 8]);
    gl_lds16(gk + kt * 64 * 64 + kof1, &sK[b][cid1 * 8]);
    gl_lds16(gv + kt * 64 + vof0, &sV[b][cid0 * 8]);
    gl_lds16(gv + kt * 64 + vof1, &sV[b][cid1 * 8]);
  };

  uint4 ou; ou.x = ou.y = ou.z = ou.w = 0x3F803F80u;   // bf16 1.0 x8
  const bf16x8 ones = __builtin_bit_cast(bf16x8, ou);

  stage(0, 0);
  __syncthreads();

#pragma unroll 2
  for (int kt = 0; kt < 32; ++kt) {
    const int cur = kt & 1;
    if (kt < 31) stage(kt + 1, cur ^ 1);   // prefetch: latency hides under compute
    const unsigned short* sk = &sK[cur][0];
    const unsigned short* sv = &sV[cur][0];

    // ---- phase A: QK^T for BOTH p halves (fills the MFMA pipe) ----
    f32x4 s[2][2][2];                       // [p][i][tt], all indices static
#pragma unroll
    for (int p = 0; p < 2; ++p) {
      bf16x8 kf[2][2];
#pragma unroll
      for (int tt = 0; tt < 2; ++tt) {
        int g = p * 32 + 8 * (lm >> 2) + (lm & 3) + 4 * tt;
        int sg = (g & 3) | ((g & 8) >> 1);
        kf[tt][0] = *(const bf16x8*)(sk + g * 64 + ((quad ^ sg) * 8));
        kf[tt][1] = *(const bf16x8*)(sk + g * 64 + (((4 + quad) ^ sg) * 8));
      }
      __builtin_amdgcn_s_setprio(1);
#pragma unroll
      for (int i = 0; i < 2; ++i) {
        f32x4 a0 = (f32x4){0.f, 0.f, 0.f, 0.f};
        f32x4 a1 = (f32x4){0.f, 0.f, 0.f, 0.f};
        a0 = mfma16(kf[0][0], qf[i][0], a0);
        a0 = mfma16(kf[0][1], qf[i][1], a0);
        a1 = mfma16(kf[1][0], qf[i][0], a1);
        a1 = mfma16(kf[1][1], qf[i][1], a1);
        s[p][i][0] = a0;
        s[p][i][1] = a1;
      }
      __builtin_amdgcn_s_setprio(0);
    }

    // ---- phase B: softmax(p) + PV(p); exp2(p=1) overlaps PV(p=0) ----
#pragma unroll
    for (int p = 0; p < 2; ++p) {
      bf16x8 pfrag[2];
#pragma unroll
      for (int i = 0; i < 2; ++i) {
        float p0[4], p1[4];
#pragma unroll
        for (int r = 0; r < 4; ++r) {
          p0[r] = __builtin_amdgcn_exp2f(s[p][i][0][r]);
          p1[r] = __builtin_amdgcn_exp2f(s[p][i][1][r]);
        }
        uint4 pw;
        pw.x = pkbf_t(p0[0], p0[1]); pw.y = pkbf_t(p0[2], p0[3]);
        pw.z = pkbf_t(p1[0], p1[1]); pw.w = pkbf_t(p1[2], p1[3]);
        pfrag[i] = __builtin_bit_cast(bf16x8, pw);
      }
      // PV: o[q][d] += P[q][k]*V[k][d]; l row-sums via ones column
      __builtin_amdgcn_s_setprio(1);
#pragma unroll
      for (int i = 0; i < 2; ++i) lacc[i] = mfma16(pfrag[i], ones, lacc[i]);
#pragma unroll
      for (int nv = 0; nv < 4; ++nv) {
        bf16x8 vb = *(const bf16x8*)(sv + (nv * 16 + lm) * 64 + (((p * 4 + quad) ^ (lm & 7)) * 8));
#pragma unroll
        for (int i = 0; i < 2; ++i) o[i][nv] = mfma16(pfrag[i], vb, o[i][nv]);
      }
      __builtin_amdgcn_s_setprio(0);
    }
    __syncthreads();   // drains this iter's prefetch (vmcnt) + LDS reads
  }

  int b = bh >> 4, h = bh & 15;
#pragma unroll
  for (int i = 0; i < 2; ++i) {
    float inv[4];
#pragma unroll
    for (int r = 0; r < 4; ++r) inv[r] = __builtin_amdgcn_rcpf(lacc[i][r]);
#pragma unroll
    for (int nv = 0; nv < 4; ++nv)
#pragma unroll
      for (int r = 0; r < 4; ++r) {
        int q = qt * 128 + w * 32 + i * 16 + quad * 4 + r;
        int d = nv * 16 + lm;
        Xw[((long)(b * 2048 + q) * 16 + h) * 64 + d] = f2bf(o[i][nv][r] * inv[r]);
      }
  }
}

// ---------- output GEMM: out = X @ Wo^T (pure bf16, fp32 out, BK=64) ----------
// Same double-buffered 2-phase schedule as proj_gemm.
__global__ __launch_bounds__(256, 2) void out_gemm(
    const unsigned short* __restrict__ A, const unsigned short* __restrict__ Bw,
    float* __restrict__ C) {
  __shared__ __align__(16) unsigned short smem[2][16384]; // 64KB
  const int t = threadIdx.x;
  const int bm = blockIdx.x, bn = blockIdx.y;
  const int lane = t & 63, lm = lane & 15, quad = lane >> 4;
  const int w = t >> 6, wr = w >> 1, wc = w & 1;

  f32x4 acc[4][4];
#pragma unroll
  for (int i = 0; i < 4; ++i)
#pragma unroll
    for (int j = 0; j < 4; ++j) acc[i][j] = (f32x4){0.f, 0.f, 0.f, 0.f};

  auto stage = [&](int kk, int b) {
#pragma unroll
    for (int jj = 0; jj < 4; ++jj) {
      int cid = jj * 256 + t;
      int r = cid >> 3, c = cid & 7;
      int gcol = kk * 64 + ((c ^ (r & 7)) * 8);
      gl_lds16(A + (bm * 128 + r) * 1024 + gcol, &smem[b][cid * 8]);
      gl_lds16(Bw + (bn * 128 + r) * 1024 + gcol, &smem[b][8192 + cid * 8]);
    }
  };

  stage(0, 0);
  __syncthreads();

  for (int kk = 0; kk < 16; ++kk) {
    const int cur = kk & 1;
    if (kk < 15) stage(kk + 1, cur ^ 1);   // prefetch: latency hides under compute
    const unsigned short* sA = &smem[cur][0];
    const unsigned short* sB = &smem[cur][8192];
#pragma unroll
    for (int kc = 0; kc < 2; ++kc) {
      bf16x8 af[4], bf[4];
#pragma unroll
      for (int i = 0; i < 4; ++i) {
        int m = wr * 64 + i * 16 + lm;
        int nn = wc * 64 + i * 16 + lm;
        int slot = ((kc * 4 + quad) ^ (lm & 7)) * 8;
        af[i] = *(const bf16x8*)(sA + m * 64 + slot);
        bf[i] = *(const bf16x8*)(sB + nn * 64 + slot);
      }
#pragma unroll
      for (int i = 0; i < 4; ++i)
#pragma unroll
        for (int j = 0; j < 4; ++j) acc[i][j] = mfma16(af[i], bf[j], acc[i][j]);
    }
    __syncthreads();
  }
#pragma unroll
  for (int i = 0; i < 4; ++i)
#pragma unroll
    for (int j = 0; j < 4; ++j)
#pragma unroll
      for (int r = 0; r < 4; ++r) {
        int m = bm * 128 + wr * 64 + i * 16 + quad * 4 + r;
        int nn = bn * 128 + wc * 64 + j * 16 + lm;
        C[m * 1024 + nn] = acc[i][j][r];
      }
}

extern "C" void kernel_launch(void* const* d_in, const int* in_sizes, int n_in,
                              void* d_out, int out_size, void* d_ws, size_t ws_size,
                              hipStream_t stream) {
  const float* q  = (const float*)d_in[0];
  const float* k  = (const float*)d_in[1];
  const float* v  = (const float*)d_in[2];
  const float* Wq = (const float*)d_in[3];
  const float* Wk = (const float*)d_in[4];
  const float* Wv = (const float*)d_in[5];
  const float* Wo = (const float*)d_in[6];

  char* ws = (char*)d_ws;
  const size_t MK = (size_t)MROWS * DMODEL;   // 8,388,608 elems
  const size_t KK = (size_t)DMODEL * DMODEL;  // 1,048,576 elems
  size_t off = 0;
  auto nxt = [&](size_t elems) { unsigned short* p = (unsigned short*)(ws + off); off += elems * 2; return p; };
  unsigned short* q_b  = nxt(MK);
  unsigned short* k_b  = nxt(MK);
  unsigned short* v_b  = nxt(MK);
  unsigned short* Wq_b = nxt(KK);
  unsigned short* Wk_b = nxt(KK);
  unsigned short* Wv_b = nxt(KK);
  unsigned short* Wo_b = nxt(KK);
  unsigned short* Qw = nxt(MK);
  unsigned short* Kw = nxt(MK);
  unsigned short* Vt = nxt(MK);
  unsigned short* Xw = q_b;   // q_b is dead after proj_gemm; flash writes Xw after
  (void)ws_size; (void)in_sizes; (void)n_in; (void)out_size;

  // (3*2097152 + 4*262144) float4-groups / 256 = 28672 blocks exactly
  cvt_all<<<28672, 256, 0, stream>>>(q, k, v, Wq, Wk, Wv, Wo,
                                     q_b, k_b, v_b, Wq_b, Wk_b, Wv_b, Wo_b);
  proj_gemm<<<dim3(64, 8, 3), 256, 0, stream>>>(q_b, k_b, v_b,
                                                Wq_b, Wk_b, Wv_b,
                                                Qw, Kw, Vt);
  flash_attn<<<dim3(8, 16, 8), 256, 0, stream>>>(Qw, Kw, Vt, Xw);
  out_gemm<<<dim3(64, 8), 256, 0, stream>>>(Xw, Wo_b, (float*)d_out);
}